// Round 5
// baseline (252.178 us; speedup 1.0000x reference)
//
#include <hip/hip_runtime.h>
#include <math.h>

#define BB 32
#define TT 4096
#define DD 768
#define NH 4
#define RELW 32
#define NREL 65
#define HIDDEN 256
#define INPROJ 1792  // DD + NH*64 + DD

#define NSTR 64      // strips per batch (64 rows each)
#define SROWS 64
#define NSTEP 32     // 2 rows per step

// ---- canonical GCN wave64 sum via DPP (VALU pipe, no DS traffic) ----
template <int CTRL, int RMASK>
__device__ __forceinline__ float upd0(float x) {
    return __int_as_float(__builtin_amdgcn_update_dpp(
        0, __float_as_int(x), CTRL, RMASK, 0xf, true));
}
__device__ __forceinline__ float wave_sum64(float x) {
    x += upd0<0x111, 0xf>(x);   // row_shr:1
    x += upd0<0x112, 0xf>(x);   // row_shr:2
    x += upd0<0x114, 0xf>(x);   // row_shr:4
    x += upd0<0x118, 0xf>(x);   // row_shr:8  -> lane15 of each row has row-sum
    x += upd0<0x142, 0xa>(x);   // row_bcast:15 into rows 1,3
    x += upd0<0x143, 0xc>(x);   // row_bcast:31 into rows 2,3 -> lane63 = total
    return __int_as_float(__builtin_amdgcn_readlane(__float_as_int(x), 63));
}

// ---------------- kernel A: h_i gather, Q = h_i*WQ, qk = (Q*WK)/8 ----------------
__global__ __launch_bounds__(256) void kA(const float* __restrict__ H,
                                          const int* __restrict__ noun_pos,
                                          const float* __restrict__ WQ,
                                          const float* __restrict__ WK,
                                          float* __restrict__ hi_ws,
                                          float* __restrict__ qk_ws) {
    int b = blockIdx.x / NH, h = blockIdx.x % NH;
    __shared__ float hi_s[DD];
    __shared__ float q_s[64];
    int tn = noun_pos[b];
    const float* Hrow = H + ((size_t)b * TT + tn) * DD;
    for (int d = threadIdx.x; d < DD; d += 256) {
        float v = Hrow[d];
        hi_s[d] = v;
        if (h == 0) hi_ws[b * DD + d] = v;
    }
    __syncthreads();
    if (threadIdx.x < 64) {
        int k = threadIdx.x;
        const float* wq = WQ + (size_t)h * DD * 64 + k;
        float acc = 0.f;
        for (int d = 0; d < DD; ++d) acc += hi_s[d] * wq[(size_t)d * 64];
        q_s[k] = acc;
    }
    __syncthreads();
    for (int d = threadIdx.x; d < DD; d += 256) {
        const float* wk = WK + ((size_t)h * DD + d) * 64;
        float acc = 0.f;
        #pragma unroll
        for (int k = 0; k < 64; ++k) acc += q_s[k] * wk[k];
        qk_ws[((size_t)b * NH + h) * DD + d] = acc * 0.125f;  // 1/sqrt(64)
    }
}

// ---------------- kFlash: 1 wave per 64-row strip, register-resident, DPP reduce ----------------
#define DOT(ACC, CV, QV) ACC += CV.x*QV.x + CV.y*QV.y + CV.z*QV.z + CV.w*QV.w

#define HUPD(M, L, S0, S1, B0, B1, B2)                                    \
  {                                                                        \
    float nm = fmaxf(M, fmaxf(S0, S1));                                    \
    if (nm > M + 8.0f) {                                                   \
      float sc = __expf(M - nm);                                           \
      L *= sc;                                                             \
      B0.x*=sc; B0.y*=sc; B0.z*=sc; B0.w*=sc;                              \
      B1.x*=sc; B1.y*=sc; B1.z*=sc; B1.w*=sc;                              \
      B2.x*=sc; B2.y*=sc; B2.z*=sc; B2.w*=sc;                              \
      M = nm;                                                              \
    }                                                                      \
    float p0 = __expf(S0 - M), p1 = __expf(S1 - M);                        \
    L += p0 + p1;                                                          \
    B0.x += p0*c0.x + p1*c3.x; B0.y += p0*c0.y + p1*c3.y;                  \
    B0.z += p0*c0.z + p1*c3.z; B0.w += p0*c0.w + p1*c3.w;                  \
    B1.x += p0*c1.x + p1*c4.x; B1.y += p0*c1.y + p1*c4.y;                  \
    B1.z += p0*c1.z + p1*c4.z; B1.w += p0*c1.w + p1*c4.w;                  \
    B2.x += p0*c2.x + p1*c5.x; B2.y += p0*c2.y + p1*c5.y;                  \
    B2.z += p0*c2.z + p1*c5.z; B2.w += p0*c2.w + p1*c5.w;                  \
  }

__global__ __launch_bounds__(64, 2) void kFlash(const float* __restrict__ H,
                                                const int* __restrict__ mask,
                                                const int* __restrict__ noun_pos,
                                                const float* __restrict__ rel_bias,
                                                const float* __restrict__ qk_ws,
                                                float* __restrict__ macc,
                                                float* __restrict__ ml) {
    const int g = blockIdx.x;
    const int b = g / NSTR, st = g % NSTR;
    const int lane = threadIdx.x;
    const int t0 = st * SROWS;
    const int tn = noun_pos[b];

    __shared__ float4 rbL[SROWS];   // 1 KB: mask-folded rel bias per strip row

    {
        int t = t0 + lane;
        int dl = t - tn; dl = dl < -RELW ? -RELW : (dl > RELW ? RELW : dl);
        float4 rv;
        if (mask[(size_t)b * TT + t]) {
            rv.x = rel_bias[0 * NREL + dl + RELW];
            rv.y = rel_bias[1 * NREL + dl + RELW];
            rv.z = rel_bias[2 * NREL + dl + RELW];
            rv.w = rel_bias[3 * NREL + dl + RELW];
        } else {
            rv.x = rv.y = rv.z = rv.w = -2.0e9f;
        }
        rbL[lane] = rv;
    }
    __syncthreads();

    // qk fragments: head h, lane's 12 floats (3 float4 at j*64+lane)
    float4 qr[NH][3];
    {
        const float4* qk4 = (const float4*)(qk_ws + (size_t)b * NH * DD);
        #pragma unroll
        for (int h = 0; h < NH; ++h)
            #pragma unroll
            for (int j = 0; j < 3; ++j)
                qr[h][j] = qk4[h * 192 + j * 64 + lane];
    }

    float m0 = -3.0e38f, m1 = -3.0e38f, m2 = -3.0e38f, m3 = -3.0e38f;
    float l0 = 0.f, l1 = 0.f, l2 = 0.f, l3 = 0.f;
    float4 A00{0,0,0,0}, A01{0,0,0,0}, A02{0,0,0,0};
    float4 A10{0,0,0,0}, A11{0,0,0,0}, A12{0,0,0,0};
    float4 A20{0,0,0,0}, A21{0,0,0,0}, A22{0,0,0,0};
    float4 A30{0,0,0,0}, A31{0,0,0,0}, A32{0,0,0,0};

    const float4* __restrict__ Hc = (const float4*)(H + ((size_t)b * TT + t0) * DD);

    // prologue: load rows 0,1
    float4 c0 = Hc[lane],        c1 = Hc[64 + lane],  c2 = Hc[128 + lane];
    float4 c3 = Hc[192 + lane],  c4 = Hc[256 + lane], c5 = Hc[320 + lane];
    float4 n0, n1, n2, n3, n4, n5;

    #pragma unroll 1
    for (int s = 0; s < NSTEP; ++s) {
        if (s + 1 < NSTEP) {   // prefetch next 2 rows into regs
            const float4* Hn = Hc + (2 * s + 2) * 192;
            n0 = Hn[lane];       n1 = Hn[64 + lane];  n2 = Hn[128 + lane];
            n3 = Hn[192 + lane]; n4 = Hn[256 + lane]; n5 = Hn[320 + lane];
        }
        // in-lane partial dots: rows (c0..c2), (c3..c5) x 4 heads
        float s00 = 0, s01 = 0, s02 = 0, s03 = 0;
        float s10 = 0, s11 = 0, s12 = 0, s13 = 0;
        DOT(s00, c0, qr[0][0]); DOT(s00, c1, qr[0][1]); DOT(s00, c2, qr[0][2]);
        DOT(s01, c0, qr[1][0]); DOT(s01, c1, qr[1][1]); DOT(s01, c2, qr[1][2]);
        DOT(s02, c0, qr[2][0]); DOT(s02, c1, qr[2][1]); DOT(s02, c2, qr[2][2]);
        DOT(s03, c0, qr[3][0]); DOT(s03, c1, qr[3][1]); DOT(s03, c2, qr[3][2]);
        DOT(s10, c3, qr[0][0]); DOT(s10, c4, qr[0][1]); DOT(s10, c5, qr[0][2]);
        DOT(s11, c3, qr[1][0]); DOT(s11, c4, qr[1][1]); DOT(s11, c5, qr[1][2]);
        DOT(s12, c3, qr[2][0]); DOT(s12, c4, qr[2][1]); DOT(s12, c5, qr[2][2]);
        DOT(s13, c3, qr[3][0]); DOT(s13, c4, qr[3][1]); DOT(s13, c5, qr[3][2]);
        // DPP reduce -> wave-uniform scores
        float r00 = wave_sum64(s00), r01 = wave_sum64(s01);
        float r02 = wave_sum64(s02), r03 = wave_sum64(s03);
        float r10 = wave_sum64(s10), r11 = wave_sum64(s11);
        float r12 = wave_sum64(s12), r13 = wave_sum64(s13);
        // rel-bias + mask (broadcast LDS read)
        float4 rb0 = rbL[2 * s], rb1 = rbL[2 * s + 1];
        r00 += rb0.x; r01 += rb0.y; r02 += rb0.z; r03 += rb0.w;
        r10 += rb1.x; r11 += rb1.y; r12 += rb1.z; r13 += rb1.w;
        // per-head online softmax + accumulate (defer-max THR=8)
        HUPD(m0, l0, r00, r10, A00, A01, A02);
        HUPD(m1, l1, r01, r11, A10, A11, A12);
        HUPD(m2, l2, r02, r12, A20, A21, A22);
        HUPD(m3, l3, r03, r13, A30, A31, A32);
        // rotate pipeline regs
        c0 = n0; c1 = n1; c2 = n2; c3 = n3; c4 = n4; c5 = n5;
    }

    // write wave partial: coalesced float4 stores
    float4* mo = (float4*)(macc + (size_t)g * NH * DD);
    mo[0 * 192 + 0 * 64 + lane] = A00; mo[0 * 192 + 64 + lane] = A01; mo[0 * 192 + 128 + lane] = A02;
    mo[1 * 192 + 0 * 64 + lane] = A10; mo[1 * 192 + 64 + lane] = A11; mo[1 * 192 + 128 + lane] = A12;
    mo[2 * 192 + 0 * 64 + lane] = A20; mo[2 * 192 + 64 + lane] = A21; mo[2 * 192 + 128 + lane] = A22;
    mo[3 * 192 + 0 * 64 + lane] = A30; mo[3 * 192 + 64 + lane] = A31; mo[3 * 192 + 128 + lane] = A32;
    if (lane == 0) {
        float* mp = ml + (size_t)g * NH * 2;
        mp[0] = m0; mp[1] = l0; mp[2] = m1; mp[3] = l1;
        mp[4] = m2; mp[5] = l2; mp[6] = m3; mp[7] = l3;
    }
}

// ---------------- transpose proj_w (HIDDEN,INPROJ) -> (INPROJ,HIDDEN) ----------------
__global__ __launch_bounds__(256) void kT(const float* __restrict__ pw,
                                          float* __restrict__ pwT) {
    int o = blockIdx.x * 256 + threadIdx.x;
    int j = o / INPROJ, i = o % INPROJ;
    pwT[(size_t)i * HIDDEN + j] = pw[o];
}

// ---------------- kD: flash-combine (64 strips) + c = hbar*WV + GELU MLP ----------------
__global__ __launch_bounds__(256) void kD(const float* __restrict__ macc,
                                          const float* __restrict__ ml,
                                          const float* __restrict__ hi_ws,
                                          const float* __restrict__ pooled,
                                          const float* __restrict__ WV,
                                          const float* __restrict__ pwT,
                                          const float* __restrict__ pb,
                                          const float* __restrict__ mw,
                                          const float* __restrict__ mb,
                                          float* __restrict__ out) {
    int b = blockIdx.x;
    __shared__ float w_s[NSTR][NH];
    __shared__ float invL_s[NH];
    __shared__ float hb_s[NH * DD];
    __shared__ float r_s[INPROJ];
    __shared__ float hdn_s[HIDDEN];

    if (threadIdx.x < NH) {
        int h = threadIdx.x;
        float M = -3.0e38f;
        for (int c = 0; c < NSTR; ++c)
            M = fmaxf(M, ml[((b * NSTR + c) * NH + h) * 2 + 0]);
        float L = 0.f;
        for (int c = 0; c < NSTR; ++c) {
            float w = __expf(ml[((b * NSTR + c) * NH + h) * 2 + 0] - M);
            w_s[c][h] = w;
            L += w * ml[((b * NSTR + c) * NH + h) * 2 + 1];
        }
        invL_s[h] = 1.f / L;
    }
    for (int i = threadIdx.x; i < DD; i += 256) {
        r_s[i] = hi_ws[b * DD + i];
        r_s[DD + NH * 64 + i] = pooled[b * DD + i];
    }
    __syncthreads();
    for (int i = threadIdx.x; i < NH * DD; i += 256) {
        int h = i / DD, d = i % DD;
        float a = 0.f;
        #pragma unroll 8
        for (int c = 0; c < NSTR; ++c)
            a += w_s[c][h] * macc[((size_t)(b * NSTR + c) * NH + h) * DD + d];
        hb_s[i] = a * invL_s[h];
    }
    __syncthreads();
    {
        int h = threadIdx.x >> 6, v = threadIdx.x & 63;
        const float* wv = WV + (size_t)h * DD * 64 + v;
        const float* hb = hb_s + h * DD;
        float acc = 0.f;
        for (int d = 0; d < DD; ++d) acc += hb[d] * wv[(size_t)d * 64];
        r_s[DD + threadIdx.x] = acc;
    }
    __syncthreads();
    {
        int j = threadIdx.x;
        float acc = pb[j];
        #pragma unroll 8
        for (int i = 0; i < INPROJ; ++i) acc += r_s[i] * pwT[(size_t)i * HIDDEN + j];
        hdn_s[j] = 0.5f * acc * (1.f + erff(acc * 0.70710678118654752f));
    }
    __syncthreads();
    float p0 = hdn_s[threadIdx.x] * mw[threadIdx.x];
    float p1 = hdn_s[threadIdx.x] * mw[HIDDEN + threadIdx.x];
    #pragma unroll
    for (int off = 32; off; off >>= 1) {
        p0 += __shfl_xor(p0, off);
        p1 += __shfl_xor(p1, off);
    }
    __shared__ float r0[4], r1[4];
    if ((threadIdx.x & 63) == 0) {
        r0[threadIdx.x >> 6] = p0;
        r1[threadIdx.x >> 6] = p1;
    }
    __syncthreads();
    if (threadIdx.x == 0) {
        out[b * 2 + 0] = r0[0] + r0[1] + r0[2] + r0[3] + mb[0];
        out[b * 2 + 1] = r1[0] + r1[1] + r1[2] + r1[3] + mb[1];
    }
}

extern "C" void kernel_launch(void* const* d_in, const int* in_sizes, int n_in,
                              void* d_out, int out_size, void* d_ws, size_t ws_size,
                              hipStream_t stream) {
    const float* H      = (const float*)d_in[0];
    const int*   mask   = (const int*)d_in[1];
    const int*   noun   = (const int*)d_in[2];
    const float* pooled = (const float*)d_in[3];
    const float* WQ     = (const float*)d_in[4];
    const float* WK     = (const float*)d_in[5];
    const float* WV     = (const float*)d_in[6];
    const float* relb   = (const float*)d_in[7];
    const float* pw     = (const float*)d_in[8];
    const float* pb     = (const float*)d_in[9];
    const float* mw     = (const float*)d_in[10];
    const float* mb     = (const float*)d_in[11];
    float* out = (float*)d_out;

    float* ws   = (float*)d_ws;
    float* hi   = ws;                                 // BB*DD          = 24576
    float* qk   = hi + BB * DD;                       // BB*NH*DD       = 98304
    float* macc = qk + BB * NH * DD;                  // BB*NSTR*NH*DD  = 6291456
    float* ml   = macc + (size_t)BB * NSTR * NH * DD; // BB*NSTR*NH*2   = 16384
    float* pwT  = ml + BB * NSTR * NH * 2;            // INPROJ*HIDDEN  = 458752

    kA<<<BB * NH, 256, 0, stream>>>(H, noun, WQ, WK, hi, qk);
    kFlash<<<BB * NSTR, 64, 0, stream>>>(H, mask, noun, relb, qk, macc, ml);
    kT<<<(HIDDEN * INPROJ) / 256, 256, 0, stream>>>(pw, pwT);
    kD<<<BB, 256, 0, stream>>>(macc, ml, hi, pooled, WV, pwT, pb, mw, mb, out);
}